// Round 1
// baseline (240.212 us; speedup 1.0000x reference)
//
#include <hip/hip_runtime.h>

// LocalConnectivity: diamond (L1-ball radius 5) circular convolution over
// (B=64, H=512, W=512) fp32, weight per L1-distance d: w_d = d_in[1][d-1].
//
// Decomposition (exact):
//   h_a[r][j] = sum_{|b| <= 5-a} w_{a+|b|} * s[r][(j+b)&511]   (h_0 excludes b=0)
//   out[i][j] = h_0[i][j] + sum_{a=1..5} (h_a[i-a][j] + h_a[i+a][j])
//
// R1 lesson: __launch_bounds__(128,4) -> 64 VGPR cap on a 124-reg kernel ->
//   scratch spills -> 724 MB HBM, 217 us.
// R2: direct global reads: 67 us, latency-bound.
// R3: LDS row-pipeline, 128 thr x 4 cols: 43.4 us rocprof. VGPR=124 ->
//   4 waves/SIMD; VALUBusy 22%, HBM 35%, Occupancy 14.7% -> latency-bound,
//   not BW/VALU-bound. acc[11][4]=44 regs is the VGPR hog.
// R4 (this): halve per-thread width: 256 thr x 2 cols (block still spans the
//   full 512-col row, so the circular halo stays in-block). acc 44->22,
//   v 20->14, h folded into scatter (transient). Live set ~56 regs ->
//   __launch_bounds__(256,8) forces <=64 VGPR -> 8 waves/SIMD, 32 waves/CU
//   (2x). Same LDS ring (6 x 512 f32 = 12 KB), same prefetch distance 2,
//   same barrier structure. Total VALU work unchanged.

#define LC_H 512
#define LC_W 512
#define LC_TY 16
#define LC_NT 256   // threads per block; each owns 2 columns
#define LC_NR (LC_TY + 10)  // 26 source rows per strip
#define LC_RS 6     // LDS ring slots

__global__ __launch_bounds__(LC_NT, 8)
void LocalConnectivity_kernel(const float* __restrict__ in,
                              const float* __restrict__ wp,
                              float* __restrict__ out) {
    const int t = threadIdx.x;            // column-pair index 0..255
    const int b = blockIdx.y;             // batch
    const int r0 = blockIdx.x * LC_TY;    // first output row of strip

    const float w1 = wp[0], w2 = wp[1], w3 = wp[2], w4 = wp[3], w5 = wp[4];

    const float* __restrict__ src = in + (size_t)b * LC_H * LC_W;
    float* __restrict__ dst = out + (size_t)b * LC_H * LC_W;

    __shared__ float lds[LC_RS * LC_W];   // 12 KB: ring of 6 source rows

    // source row j (0..25) lives at grid row (r0 + j - 5) & 511, LDS slot j%6
    auto row_ptr = [&](int j) -> const float* {
        return src + ((r0 + j - 5) & (LC_H - 1)) * LC_W;
    };

    float acc[11][2];
#pragma unroll
    for (int k = 0; k < 11; ++k) { acc[k][0] = 0.f; acc[k][1] = 0.f; }

    // ---- pipeline prologue: rows 0..2 -> LDS slots 0..2; rows 3,4 -> regs
    float2 fpre[3];
#pragma unroll
    for (int j = 0; j < 3; ++j) {
        const float2 f = *reinterpret_cast<const float2*>(row_ptr(j) + t * 2);
        *reinterpret_cast<float2*>(&lds[j * LC_W + t * 2]) = f;
    }
    fpre[1] = *reinterpret_cast<const float2*>(row_ptr(3) + t * 2);
    fpre[2] = *reinterpret_cast<const float2*>(row_ptr(4) + t * 2);

#pragma unroll
    for (int rr = 0; rr < LC_NR; ++rr) {
        __syncthreads();

        // stage row rr+3 (loaded 2 iters ago) into slot (rr+3)%6
        if (rr + 3 < LC_NR) {
            const float2 f = fpre[(rr + 1) % 3];
            *reinterpret_cast<float2*>(&lds[((rr + 3) % LC_RS) * LC_W + t * 2]) = f;
        }
        // prefetch row rr+5 from global (consumed at iter rr+2)
        if (rr + 5 < LC_NR) {
            fpre[rr % 3] = *reinterpret_cast<const float2*>(row_ptr(rr + 5) + t * 2);
        }

        // read 14 columns (cols 2t-6 .. 2t+7) of source row rr from LDS
        float v[14];
        const float* slotp = &lds[(rr % LC_RS) * LC_W];
#pragma unroll
        for (int o = 0; o < 7; ++o) {
            const int cb = (t + o - 3) & (LC_NT - 1);
            const float2 f = *reinterpret_cast<const float2*>(slotp + cb * 2);
            v[o * 2 + 0] = f.x;
            v[o * 2 + 1] = f.y;
        }

        // horizontal pass + vertical scatter fused: v[6+q] is my column q
        // (global 2t+q). h values are transient (folded into acc at once).
        const int r_off = rr - 5;
#pragma unroll
        for (int q = 0; q < 2; ++q) {
            const float p0 = v[6 + q];
            const float p1 = v[5 + q] + v[7 + q];
            const float p2 = v[4 + q] + v[8 + q];
            const float p3 = v[3 + q] + v[9 + q];
            const float p4 = v[2 + q] + v[10 + q];
            const float p5 = v[1 + q] + v[11 + q];

            float hv;
            // a = 0 -> output row r_off
            hv = w1 * p1 + w2 * p2 + w3 * p3 + w4 * p4 + w5 * p5;
            if (r_off >= 0 && r_off < LC_TY) acc[r_off % 11][q] += hv;
            // a = 1 -> r_off +- 1
            hv = w1 * p0 + w2 * p1 + w3 * p2 + w4 * p3 + w5 * p4;
            {
                const int op = r_off + 1, om = r_off - 1;
                if (op >= 0 && op < LC_TY) acc[op % 11][q] += hv;
                if (om >= 0 && om < LC_TY) acc[om % 11][q] += hv;
            }
            // a = 2
            hv = w2 * p0 + w3 * p1 + w4 * p2 + w5 * p3;
            {
                const int op = r_off + 2, om = r_off - 2;
                if (op >= 0 && op < LC_TY) acc[op % 11][q] += hv;
                if (om >= 0 && om < LC_TY) acc[om % 11][q] += hv;
            }
            // a = 3
            hv = w3 * p0 + w4 * p1 + w5 * p2;
            {
                const int op = r_off + 3, om = r_off - 3;
                if (op >= 0 && op < LC_TY) acc[op % 11][q] += hv;
                if (om >= 0 && om < LC_TY) acc[om % 11][q] += hv;
            }
            // a = 4
            hv = w4 * p0 + w5 * p1;
            {
                const int op = r_off + 4, om = r_off - 4;
                if (op >= 0 && op < LC_TY) acc[op % 11][q] += hv;
                if (om >= 0 && om < LC_TY) acc[om % 11][q] += hv;
            }
            // a = 5
            hv = w5 * p0;
            {
                const int op = r_off + 5, om = r_off - 5;
                if (op >= 0 && op < LC_TY) acc[op % 11][q] += hv;
                if (om >= 0 && om < LC_TY) acc[om % 11][q] += hv;
            }
        }

        // output row oc = rr - 10 complete after this source row
        const int oc = rr - 10;
        if (oc >= 0 && oc < LC_TY) {
            const int slot = oc % 11;
            float2 f;
            f.x = acc[slot][0];
            f.y = acc[slot][1];
            *reinterpret_cast<float2*>(dst + (r0 + oc) * LC_W + t * 2) = f;
            acc[slot][0] = 0.f;
            acc[slot][1] = 0.f;
        }
    }
}

extern "C" void kernel_launch(void* const* d_in, const int* in_sizes, int n_in,
                              void* d_out, int out_size, void* d_ws, size_t ws_size,
                              hipStream_t stream) {
    const float* grid_spikes = (const float*)d_in[0];       // 64*512*512 fp32
    const float* distance_weights = (const float*)d_in[1];  // 5 fp32
    float* out = (float*)d_out;

    dim3 grid(LC_H / LC_TY, 64);  // 32 strips x 64 batches
    dim3 block(LC_NT);
    LocalConnectivity_kernel<<<grid, block, 0, stream>>>(grid_spikes, distance_weights, out);
}

// Round 2
// 136.103 us; speedup vs baseline: 1.7649x; 1.7649x over previous
//
#include <hip/hip_runtime.h>

// LocalConnectivity: diamond (L1-ball radius 5) circular convolution over
// (B=64, H=512, W=512) fp32, weight per L1-distance d: w_d = d_in[1][d-1].
//
// Decomposition (exact):
//   h_a[r][j] = sum_{|b| <= 5-a} w_{a+|b|} * s[r][(j+b)&511]   (h_0 excludes b=0)
//   out[i][j] = h_0[i][j] + sum_{a=1..5} (h_a[i-a][j] + h_a[i+a][j])
//
// R1 lesson: __launch_bounds__(128,4) on a 124-reg kernel -> spills -> 217 us.
// R2: direct global reads: 67 us, latency-bound.
// R3: LDS row pipeline, 128 thr x 4 cols: 43.4 us. VGPR=124 -> 4 waves/SIMD,
//   VALU 22%, HBM 35%, Occ 14.7% -> latency/occupancy-bound.
// R4 FAILED: 256 thr x 2 cols + __launch_bounds__(256,8): forced cap ->
//   allocator collapse (VGPR=32) + scratch spills (WRITE 65->403 MB), 157 us.
//   Lesson: must fit 64 VGPRs NATURALLY, never by force.
// R5 (this): 512 thr x 1 col. acc[11][1]=11 regs, v[11] transient, fpre ring
//   eliminated via __builtin_amdgcn_global_load_lds (async global->LDS DMA:
//   lane l -> base+4l, exactly our linear row layout; per-lane global src).
//   Est. live set ~45 regs -> <=64 naturally -> 8 waves/SIMD, 32 waves/CU.
//   No launch-bounds forcing. Same 6-slot LDS ring, one barrier/iter,
//   prefetch distance: issue row rr+2 after barrier rr (drained at rr+1,
//   consumed at rr+2). Scalar LDS halo reads: lanes l and l+32 share a bank
//   = 2-way alias = free (m136). All ring/guard indices fold via full unroll.

#define LC_H 512
#define LC_W 512
#define LC_TY 16
#define LC_NT 512   // one thread per column
#define LC_NR (LC_TY + 10)  // 26 source rows per strip
#define LC_RS 6     // LDS ring slots

typedef const __attribute__((address_space(1))) void* lc_gvp;
typedef __attribute__((address_space(3))) void* lc_lvp;

__global__ __launch_bounds__(LC_NT)
void LocalConnectivity_kernel(const float* __restrict__ in,
                              const float* __restrict__ wp,
                              float* __restrict__ out) {
    const int t = threadIdx.x;            // column 0..511
    const int b = blockIdx.y;             // batch
    const int r0 = blockIdx.x * LC_TY;    // first output row of strip

    const float w1 = wp[0], w2 = wp[1], w3 = wp[2], w4 = wp[3], w5 = wp[4];

    const float* __restrict__ src = in + (size_t)b * (LC_H * LC_W);
    float* __restrict__ dst = out + (size_t)b * (LC_H * LC_W);

    __shared__ float lds[LC_RS * LC_W];   // 12 KB: ring of 6 source rows

    // async DMA of source row j (grid row (r0+j-5)&511) into slot j%6.
    // LDS dest is wave-uniform base + lane*4 (linear) -- matches layout.
#define LC_ISSUE(j)                                                         \
    __builtin_amdgcn_global_load_lds(                                       \
        (lc_gvp)(src + ((r0 + (j) - 5) & (LC_H - 1)) * LC_W + t),           \
        (lc_lvp)(&lds[((j) % LC_RS) * LC_W + t]), 4, 0, 0)

    float acc[11];
#pragma unroll
    for (int k = 0; k < 11; ++k) acc[k] = 0.f;

    // pipeline prologue: rows 0,1 in flight (drained at first barrier)
    LC_ISSUE(0);
    LC_ISSUE(1);

#pragma unroll
    for (int rr = 0; rr < LC_NR; ++rr) {
        __syncthreads();   // drains vmcnt: row rr (issued at rr-2) is ready

        // prefetch row rr+2 into slot (rr+2)%6; its previous occupant
        // (row rr-4) was last read at iter rr-4, >=1 barrier ago.
        if (rr + 2 < LC_NR) LC_ISSUE(rr + 2);

        // halo columns t-5..t+5 of source row rr from LDS
        const float* slotp = &lds[(rr % LC_RS) * LC_W];
        float v[11];
#pragma unroll
        for (int k = 0; k < 11; ++k)
            v[k] = slotp[(t + k - 5) & (LC_W - 1)];

        const float p0 = v[5];
        const float p1 = v[4] + v[6];
        const float p2 = v[3] + v[7];
        const float p3 = v[2] + v[8];
        const float p4 = v[1] + v[9];
        const float p5 = v[0] + v[10];

        const float h0 = w1 * p1 + w2 * p2 + w3 * p3 + w4 * p4 + w5 * p5;
        const float h1 = w1 * p0 + w2 * p1 + w3 * p2 + w4 * p3 + w5 * p4;
        const float h2 = w2 * p0 + w3 * p1 + w4 * p2 + w5 * p3;
        const float h3 = w3 * p0 + w4 * p1 + w5 * p2;
        const float h4 = w4 * p0 + w5 * p1;
        const float h5 = w5 * p0;

        // vertical scatter: source row rr contributes h_a to outputs r_off+-a.
        // r_off is a compile-time constant per unrolled iter -> all guards and
        // %11 ring indices fold; acc stays in named registers.
        const int r_off = rr - 5;
        if (r_off >= 0 && r_off < LC_TY) acc[r_off % 11] += h0;
        {
            const int op = r_off + 1, om = r_off - 1;
            if (op >= 0 && op < LC_TY) acc[op % 11] += h1;
            if (om >= 0 && om < LC_TY) acc[om % 11] += h1;
        }
        {
            const int op = r_off + 2, om = r_off - 2;
            if (op >= 0 && op < LC_TY) acc[op % 11] += h2;
            if (om >= 0 && om < LC_TY) acc[om % 11] += h2;
        }
        {
            const int op = r_off + 3, om = r_off - 3;
            if (op >= 0 && op < LC_TY) acc[op % 11] += h3;
            if (om >= 0 && om < LC_TY) acc[om % 11] += h3;
        }
        {
            const int op = r_off + 4, om = r_off - 4;
            if (op >= 0 && op < LC_TY) acc[op % 11] += h4;
            if (om >= 0 && om < LC_TY) acc[om % 11] += h4;
        }
        {
            const int op = r_off + 5, om = r_off - 5;
            if (op >= 0 && op < LC_TY) acc[op % 11] += h5;
            if (om >= 0 && om < LC_TY) acc[om % 11] += h5;
        }

        // output row oc = rr - 10 complete after this source row
        const int oc = rr - 10;
        if (oc >= 0 && oc < LC_TY) {
            dst[(size_t)(r0 + oc) * LC_W + t] = acc[oc % 11];
            acc[oc % 11] = 0.f;
        }
    }
#undef LC_ISSUE
}

extern "C" void kernel_launch(void* const* d_in, const int* in_sizes, int n_in,
                              void* d_out, int out_size, void* d_ws, size_t ws_size,
                              hipStream_t stream) {
    const float* grid_spikes = (const float*)d_in[0];       // 64*512*512 fp32
    const float* distance_weights = (const float*)d_in[1];  // 5 fp32
    float* out = (float*)d_out;

    dim3 grid(LC_H / LC_TY, 64);  // 32 strips x 64 batches
    dim3 block(LC_NT);
    LocalConnectivity_kernel<<<grid, block, 0, stream>>>(grid_spikes, distance_weights, out);
}